// Round 1
// baseline (403.191 us; speedup 1.0000x reference)
//
#include <hip/hip_runtime.h>
#include <hip/hip_bf16.h>

typedef float f32x4 __attribute__((ext_vector_type(4)));
typedef __bf16 bf16x8 __attribute__((ext_vector_type(8)));
typedef unsigned short u16x4 __attribute__((ext_vector_type(4)));

#if defined(__has_builtin)
#if __has_builtin(__builtin_amdgcn_exp2f)
#define EXP2F(x) __builtin_amdgcn_exp2f(x)
#else
#define EXP2F(x) exp2f(x)
#endif
#if __has_builtin(__builtin_amdgcn_rcpf)
#define RCPF(x) __builtin_amdgcn_rcpf(x)
#else
#define RCPF(x) (1.0f/(x))
#endif
#else
#define EXP2F(x) exp2f(x)
#define RCPF(x) (1.0f/(x))
#endif

#define MFMA16(a,b,c) __builtin_amdgcn_mfma_f32_16x16x32_bf16((a),(b),(c),0,0,0)

__device__ __forceinline__ unsigned short f2bf(float f) {
  return __builtin_bit_cast(unsigned short, (__bf16)f);
}

// Build W1^T as bf16 [512 j][128 i] in d_ws (fwd A-fragment friendly: i-contiguous).
__global__ __launch_bounds__(256) void hn_prep(const float* __restrict__ W1,
                                               unsigned short* __restrict__ W1T) {
  int t = blockIdx.x * 256 + threadIdx.x;  // t = j*128 + i
  int j = t >> 7, i = t & 127;
  W1T[t] = f2bf(W1[i * 512 + j]);
}

// One block = 256 batch rows (8 waves x 32 rows). All 10 steps in-kernel.
__global__ __launch_bounds__(512, 2) void hn_main(
    const float* __restrict__ x, const float* __restrict__ W1,
    const float* __restrict__ b1, const float* __restrict__ W2,
    const unsigned short* __restrict__ W1T, float* __restrict__ out) {
  // LDS: W1 bf16 [128 i][512 j] XOR-swizzled (bwd B-frags) + tables + per-wave 2KB bounce
  __shared__ __align__(16) char w1l[131072];
  __shared__ __align__(16) float b1s[512];
  __shared__ __align__(16) float w2s[512];
  __shared__ __align__(16) char scr[8][2048];

  const int tid = threadIdx.x;
  const int lane = tid & 63;
  const int w = tid >> 6;
  const int m = lane & 15;   // l&15
  const int g = lane >> 4;   // lane group 0..3

  // ---- stage W1 -> LDS bf16 [i][512 j], byte addr = (i*1024 + j*2) ^ ((i&7)<<4)
  for (int it = tid; it < 16384; it += 512) {
    int flat = it << 2;            // element index = i*512 + j
    int i = flat >> 9;
    f32x4 v = *(const f32x4*)(W1 + flat);
    u16x4 pk;
#pragma unroll
    for (int c = 0; c < 4; ++c) pk[c] = f2bf(v[c]);
    int ba = flat << 1;            // i*1024 + j*2
    *(u16x4*)(w1l + (ba ^ ((i & 7) << 4))) = pk;
  }
  if (tid < 512) { b1s[tid] = b1[tid]; w2s[tid] = W2[tid]; }
  __syncthreads();

  const int b0 = blockIdx.x * 256 + w * 32;

  // q/p state in A/B-fragment layout: [bf][kb][r] = row (b0+m+16bf), col (kb*32+g*8+r)
  float q[2][4][8], p[2][4][8];
#pragma unroll
  for (int bf = 0; bf < 2; ++bf)
#pragma unroll
    for (int kb = 0; kb < 4; ++kb) {
      const float* r0 = x + (long)(b0 + m + 16 * bf) * 256 + kb * 32 + g * 8;
      f32x4 a0 = *(const f32x4*)r0;
      f32x4 a1 = *(const f32x4*)(r0 + 4);
      f32x4 c0 = *(const f32x4*)(r0 + 128);
      f32x4 c1 = *(const f32x4*)(r0 + 132);
#pragma unroll
      for (int r = 0; r < 4; ++r) {
        q[bf][kb][r] = a0[r]; q[bf][kb][r + 4] = a1[r];
        p[bf][kb][r] = c0[r]; p[bf][kb][r + 4] = c1[r];
      }
    }

  const char* w1tb = (const char*)W1T;
  char* st = scr[w];

#pragma unroll 1
  for (int step = 0; step < 10; ++step) {
    f32x4 gacc[2][8];  // g[b=4g+rr+16mf][i=m+16nf]
#pragma unroll
    for (int mf = 0; mf < 2; ++mf)
#pragma unroll
      for (int nf = 0; nf < 8; ++nf) gacc[mf][nf] = f32x4{0.f, 0.f, 0.f, 0.f};

#pragma unroll 1
    for (int jblk = 0; jblk < 16; ++jblk) {
      // ---- forward: Z^T tile (32 j x 32 b), A = W1^T from global, B = q regs
      f32x4 z[2][2];
      z[0][0] = f32x4{0.f,0.f,0.f,0.f}; z[0][1] = f32x4{0.f,0.f,0.f,0.f};
      z[1][0] = f32x4{0.f,0.f,0.f,0.f}; z[1][1] = f32x4{0.f,0.f,0.f,0.f};
#pragma unroll
      for (int kb = 0; kb < 4; ++kb) {
        bf16x8 qb0, qb1;
#pragma unroll
        for (int r = 0; r < 8; ++r) {
          qb0[r] = (__bf16)q[0][kb][r];
          qb1[r] = (__bf16)q[1][kb][r];
        }
#pragma unroll
        for (int jf = 0; jf < 2; ++jf) {
          bf16x8 a = *(const bf16x8*)(
              w1tb + (((jblk * 32 + jf * 16 + m) * 128 + kb * 32 + g * 8) << 1));
          z[jf][0] = MFMA16(a, qb0, z[jf][0]);
          z[jf][1] = MFMA16(a, qb1, z[jf][1]);
        }
      }
      // ---- activation + scale -> s tile [32 b][32 j] bf16, ^((b&3)<<4)
#pragma unroll
      for (int jf = 0; jf < 2; ++jf) {
        int jb = jblk * 32 + jf * 16 + 4 * g;
        f32x4 b1v = *(const f32x4*)(b1s + jb);
        f32x4 w2v = *(const f32x4*)(w2s + jb);
#pragma unroll
        for (int bf = 0; bf < 2; ++bf) {
          int brow = m + 16 * bf;
          u16x4 pk;
#pragma unroll
          for (int rr = 0; rr < 4; ++rr) {
            float zz = z[jf][bf][rr] + b1v[rr];
            float e = EXP2F(zz * 2.88539008177792681f);   // e^(2z)
            float th = 1.f - 2.f * RCPF(e + 1.f);         // tanh(z)
            float s = w2v[rr] * (1.f - th * th);
            pk[rr] = f2bf(s);
          }
          int ba = brow * 64 + (jf * 16 + 4 * g) * 2;
          *(u16x4*)(st + (ba ^ ((brow & 3) << 4))) = pk;
        }
      }
      // ---- backward accumulate: g += s @ W1^T (A = s tile, B = W1 from LDS)
      bf16x8 sA[2];
#pragma unroll
      for (int mf = 0; mf < 2; ++mf) {
        int brow = m + 16 * mf;
        int ba = brow * 64 + g * 16;
        sA[mf] = *(const bf16x8*)(st + (ba ^ ((brow & 3) << 4)));
      }
#pragma unroll
      for (int nf = 0; nf < 8; ++nf) {
        int irow = m + 16 * nf;
        int ba = irow * 1024 + (jblk * 32 + g * 8) * 2;
        bf16x8 bfr = *(const bf16x8*)(w1l + (ba ^ ((irow & 7) << 4)));
        gacc[0][nf] = MFMA16(sA[0], bfr, gacc[0][nf]);
        gacc[1][nf] = MFMA16(sA[1], bfr, gacc[1][nf]);
      }
    }

    // q += dt * p_old (g was computed from old q)
#pragma unroll
    for (int bf = 0; bf < 2; ++bf)
#pragma unroll
      for (int kb = 0; kb < 4; ++kb)
#pragma unroll
        for (int r = 0; r < 8; ++r)
          q[bf][kb][r] = fmaf(0.1f, p[bf][kb][r], q[bf][kb][r]);

    // bounce g (C-layout -> frag layout) through LDS in 32-i chunks; p -= dt*g
#pragma unroll
    for (int kb = 0; kb < 4; ++kb) {
#pragma unroll
      for (int mf = 0; mf < 2; ++mf)
#pragma unroll
        for (int h = 0; h < 2; ++h) {
          f32x4 gv = gacc[mf][kb * 2 + h];
#pragma unroll
          for (int rr = 0; rr < 4; ++rr) {
            int brow = 4 * g + rr + 16 * mf;
            int ba = brow * 64 + (m + 16 * h) * 2;
            *(unsigned short*)(st + (ba ^ ((brow & 3) << 4))) = f2bf(gv[rr]);
          }
        }
#pragma unroll
      for (int bf = 0; bf < 2; ++bf) {
        int brow = m + 16 * bf;
        int ba = brow * 64 + g * 16;
        bf16x8 gv8 = *(const bf16x8*)(st + (ba ^ ((brow & 3) << 4)));
#pragma unroll
        for (int r = 0; r < 8; ++r)
          p[bf][kb][r] = fmaf(-0.1f, (float)gv8[r], p[bf][kb][r]);
      }
    }
    __syncthreads();  // keep waves phase-locked (L1 locality on W1T slices)
  }

  // ---- store concat(q, p)
#pragma unroll
  for (int bf = 0; bf < 2; ++bf)
#pragma unroll
    for (int kb = 0; kb < 4; ++kb) {
      float* o = out + (long)(b0 + m + 16 * bf) * 256 + kb * 32 + g * 8;
      f32x4 a0, a1, c0, c1;
#pragma unroll
      for (int r = 0; r < 4; ++r) {
        a0[r] = q[bf][kb][r]; a1[r] = q[bf][kb][r + 4];
        c0[r] = p[bf][kb][r]; c1[r] = p[bf][kb][r + 4];
      }
      *(f32x4*)o = a0; *(f32x4*)(o + 4) = a1;
      *(f32x4*)(o + 128) = c0; *(f32x4*)(o + 132) = c1;
    }
}

extern "C" void kernel_launch(void* const* d_in, const int* in_sizes, int n_in,
                              void* d_out, int out_size, void* d_ws, size_t ws_size,
                              hipStream_t stream) {
  const float* x  = (const float*)d_in[0];
  const float* W1 = (const float*)d_in[1];
  const float* b1 = (const float*)d_in[2];
  const float* W2 = (const float*)d_in[3];
  // d_in[4] = b2: affects only V's value, not its gradient -> unused.
  float* out = (float*)d_out;
  unsigned short* w1t = (unsigned short*)d_ws;  // 128 KB bf16 W1^T

  hipLaunchKernelGGL(hn_prep, dim3(256), dim3(256), 0, stream, W1, w1t);
  hipLaunchKernelGGL(hn_main, dim3(256), dim3(512), 0, stream,
                     x, W1, b1, W2, w1t, out);
}

// Round 2
// 391.895 us; speedup vs baseline: 1.0288x; 1.0288x over previous
//
#include <hip/hip_runtime.h>
#include <hip/hip_bf16.h>

typedef float f32x4 __attribute__((ext_vector_type(4)));
typedef __bf16 bf16x8 __attribute__((ext_vector_type(8)));
typedef unsigned short u16x4 __attribute__((ext_vector_type(4)));
typedef unsigned int u32;
typedef unsigned int u32x4 __attribute__((ext_vector_type(4)));

#if defined(__has_builtin)
#if __has_builtin(__builtin_amdgcn_exp2f)
#define EXP2F(x) __builtin_amdgcn_exp2f(x)
#else
#define EXP2F(x) exp2f(x)
#endif
#if __has_builtin(__builtin_amdgcn_rcpf)
#define RCPF(x) __builtin_amdgcn_rcpf(x)
#else
#define RCPF(x) (1.0f/(x))
#endif
#else
#define EXP2F(x) exp2f(x)
#define RCPF(x) (1.0f/(x))
#endif

#define MFMA16(a,b,c) __builtin_amdgcn_mfma_f32_16x16x32_bf16((a),(b),(c),0,0,0)

__device__ __forceinline__ unsigned short f2bf(float f) {
  return __builtin_bit_cast(unsigned short, (__bf16)f);
}

// pack two f32 -> one u32 of 2 bf16 (RNE), lo = a, hi = b
__device__ __forceinline__ u32 pkbf(float a, float b) {
  u32 d;
  asm("v_cvt_pk_bf16_f32 %0, %1, %2" : "=v"(d) : "v"(a), "v"(b));
  return d;
}

// quad-lane exchange: C-layout 4-runs -> B-frag 8-runs.
// inputs: lo = packed pair from lower 16-block (jf/nf-even), hi = upper.
// outputs w[0..3]: B-frag words t (k = 8*g + 2t, 2t+1).
__device__ __forceinline__ void quad_exch(u32 lo0, u32 hi0, u32 lo1, u32 hi1,
                                          bool o16, u32 w[4]) {
  asm("v_permlane32_swap_b32 %0, %1" : "+v"(lo0), "+v"(hi0));
  asm("v_permlane32_swap_b32 %0, %1" : "+v"(lo1), "+v"(hi1));
  u32 xlo0 = __builtin_amdgcn_ds_swizzle((int)lo0, 0x401F);
  u32 xhi0 = __builtin_amdgcn_ds_swizzle((int)hi0, 0x401F);
  u32 xlo1 = __builtin_amdgcn_ds_swizzle((int)lo1, 0x401F);
  u32 xhi1 = __builtin_amdgcn_ds_swizzle((int)hi1, 0x401F);
  w[0] = o16 ? xhi0 : lo0;
  w[1] = o16 ? xhi1 : lo1;
  w[2] = o16 ? hi0 : xlo0;
  w[3] = o16 ? hi1 : xlo1;
}

// Build W1^T as bf16 [512 j][128 i] in d_ws (fwd A-frags: i-contiguous).
__global__ __launch_bounds__(256) void hn_prep(const float* __restrict__ W1,
                                               unsigned short* __restrict__ W1T) {
  int t = blockIdx.x * 256 + threadIdx.x;  // t = j*128 + i
  int j = t >> 7, i = t & 127;
  W1T[t] = f2bf(W1[i * 512 + j]);
}

// One block = 256 batch rows (8 waves x 32 rows). All 10 steps in-kernel.
__global__ __launch_bounds__(512, 2) void hn_main(
    const float* __restrict__ x, const float* __restrict__ W1,
    const float* __restrict__ b1, const float* __restrict__ W2,
    const unsigned short* __restrict__ W1T, float* __restrict__ out) {
  __shared__ __align__(16) char w1l[131072];  // W1 bf16 [128 i][512 j], ^((i&7)<<4)
  __shared__ __align__(16) float b1s[512];    // pre-scaled b1 * 2*log2(e)
  __shared__ __align__(16) float w2s[512];

  const int tid = threadIdx.x;
  const int lane = tid & 63;
  const int w = tid >> 6;
  const int m = lane & 15;
  const int g = lane >> 4;
  const bool o16 = (g & 1);

  // ---- stage W1 -> LDS
  for (int it = tid; it < 16384; it += 512) {
    int flat = it << 2;            // element index = i*512 + j
    int i = flat >> 9;
    f32x4 v = *(const f32x4*)(W1 + flat);
    u16x4 pk;
#pragma unroll
    for (int c = 0; c < 4; ++c) pk[c] = f2bf(v[c]);
    int ba = flat << 1;
    *(u16x4*)(w1l + (ba ^ ((i & 7) << 4))) = pk;
  }
  if (tid < 512) {
    b1s[tid] = b1[tid] * 2.8853900817779268f;
    w2s[tid] = W2[tid];
  }
  __syncthreads();

  const int b0 = blockIdx.x * 256 + w * 32;

  // q/p state in B-frag layout: [bf][kb][r] = row (b0+m+16bf), col i = kb*32+g*8+r
  float q[2][4][8], p[2][4][8];
#pragma unroll
  for (int bf = 0; bf < 2; ++bf)
#pragma unroll
    for (int kb = 0; kb < 4; ++kb) {
      const float* r0 = x + (long)(b0 + m + 16 * bf) * 256 + kb * 32 + g * 8;
      f32x4 a0 = *(const f32x4*)r0;
      f32x4 a1 = *(const f32x4*)(r0 + 4);
      f32x4 c0 = *(const f32x4*)(r0 + 128);
      f32x4 c1 = *(const f32x4*)(r0 + 132);
#pragma unroll
      for (int r = 0; r < 4; ++r) {
        q[bf][kb][r] = a0[r]; q[bf][kb][r + 4] = a1[r];
        p[bf][kb][r] = c0[r]; p[bf][kb][r + 4] = c1[r];
      }
    }

  // lane-constant addresses
  const char* aptr = (const char*)W1T + m * 256 + g * 16;  // (m*128+g*8)*2
  const int s45 = (m & 3) << 4, s6 = (m & 4) << 4;
  const int ybase = ((m * 1024 + g * 16) ^ s45);

#pragma unroll 1
  for (int step = 0; step < 10; ++step) {
    f32x4 gacc[2][8];  // g^T[i=16nf+4g+rr][b=16bf+m]
#pragma unroll
    for (int bf = 0; bf < 2; ++bf)
#pragma unroll
      for (int nf = 0; nf < 8; ++nf) gacc[bf][nf] = f32x4{0.f, 0.f, 0.f, 0.f};

#pragma unroll 1
    for (int jblk = 0; jblk < 16; ++jblk) {
      // ---- forward: Z^T tile (32 j x 32 b). A = W1^T j-rows (global/L1), B = q.
      f32x4 z[2][2];
      z[0][0] = f32x4{0.f,0.f,0.f,0.f}; z[0][1] = f32x4{0.f,0.f,0.f,0.f};
      z[1][0] = f32x4{0.f,0.f,0.f,0.f}; z[1][1] = f32x4{0.f,0.f,0.f,0.f};
#pragma unroll
      for (int kb = 0; kb < 4; ++kb) {
        bf16x8 qb0, qb1;
        {
          u32x4 w0, w1v;
#pragma unroll
          for (int h = 0; h < 4; ++h) {
            w0[h]  = pkbf(q[0][kb][2 * h], q[0][kb][2 * h + 1]);
            w1v[h] = pkbf(q[1][kb][2 * h], q[1][kb][2 * h + 1]);
          }
          qb0 = __builtin_bit_cast(bf16x8, w0);
          qb1 = __builtin_bit_cast(bf16x8, w1v);
        }
#pragma unroll
        for (int jf = 0; jf < 2; ++jf) {
          bf16x8 a = *(const bf16x8*)(aptr + jblk * 8192 + jf * 4096 + kb * 64);
          z[jf][0] = MFMA16(a, qb0, z[jf][0]);
          z[jf][1] = MFMA16(a, qb1, z[jf][1]);
        }
      }
      // ---- activation: s = W2 * (1 - tanh(z+b1)^2)
      float s4[2][2][4];  // [jf][bf][rr]
#pragma unroll
      for (int jf = 0; jf < 2; ++jf) {
        int jb = jblk * 32 + jf * 16 + 4 * g;
        f32x4 b1v = *(const f32x4*)(b1s + jb);
        f32x4 w2v = *(const f32x4*)(w2s + jb);
#pragma unroll
        for (int bf = 0; bf < 2; ++bf)
#pragma unroll
          for (int rr = 0; rr < 4; ++rr) {
            float zz = fmaf(z[jf][bf][rr], 2.8853900817779268f, b1v[rr]);
            float e = EXP2F(zz);                 // e^(2(z+b1))
            float u = RCPF(e + 1.f);
            float th = fmaf(-2.f, u, 1.f);       // tanh
            s4[jf][bf][rr] = fmaf(-th * th, w2v[rr], w2v[rr]);
          }
      }
      // ---- s C-layout -> B-frags via quad exchange, then bwd MFMA
      bf16x8 sB[2];
#pragma unroll
      for (int bf = 0; bf < 2; ++bf) {
        u32 Bw[4];
        quad_exch(pkbf(s4[0][bf][0], s4[0][bf][1]), pkbf(s4[1][bf][0], s4[1][bf][1]),
                  pkbf(s4[0][bf][2], s4[0][bf][3]), pkbf(s4[1][bf][2], s4[1][bf][3]),
                  o16, Bw);
        u32x4 wv; wv[0] = Bw[0]; wv[1] = Bw[1]; wv[2] = Bw[2]; wv[3] = Bw[3];
        sB[bf] = __builtin_bit_cast(bf16x8, wv);
      }
      const int joff = (jblk * 64) ^ s6;
#pragma unroll
      for (int nf = 0; nf < 8; ++nf) {
        bf16x8 af = *(const bf16x8*)(w1l + ybase + nf * 16384 + joff);
        gacc[0][nf] = MFMA16(af, sB[0], gacc[0][nf]);
        gacc[1][nf] = MFMA16(af, sB[1], gacc[1][nf]);
      }
    }

    // q += dt * p_old (g was computed from old q)
#pragma unroll
    for (int bf = 0; bf < 2; ++bf)
#pragma unroll
      for (int kb = 0; kb < 4; ++kb)
#pragma unroll
        for (int r = 0; r < 8; ++r)
          q[bf][kb][r] = fmaf(0.1f, p[bf][kb][r], q[bf][kb][r]);

    // gacc (C-layout) -> p-frag layout via quad exchange; p -= dt*g
#pragma unroll
    for (int bf = 0; bf < 2; ++bf)
#pragma unroll
      for (int kb = 0; kb < 4; ++kb) {
        u32 Gw[4];
        quad_exch(pkbf(gacc[bf][2*kb][0],   gacc[bf][2*kb][1]),
                  pkbf(gacc[bf][2*kb+1][0], gacc[bf][2*kb+1][1]),
                  pkbf(gacc[bf][2*kb][2],   gacc[bf][2*kb][3]),
                  pkbf(gacc[bf][2*kb+1][2], gacc[bf][2*kb+1][3]),
                  o16, Gw);
#pragma unroll
        for (int t = 0; t < 4; ++t) {
          float glo = __builtin_bit_cast(float, Gw[t] << 16);
          float ghi = __builtin_bit_cast(float, Gw[t] & 0xffff0000u);
          p[bf][kb][2 * t]     = fmaf(-0.1f, glo, p[bf][kb][2 * t]);
          p[bf][kb][2 * t + 1] = fmaf(-0.1f, ghi, p[bf][kb][2 * t + 1]);
        }
      }
    __syncthreads();  // phase-lock waves for W1T L1 locality
  }

  // ---- store concat(q, p)
#pragma unroll
  for (int bf = 0; bf < 2; ++bf)
#pragma unroll
    for (int kb = 0; kb < 4; ++kb) {
      float* o = out + (long)(b0 + m + 16 * bf) * 256 + kb * 32 + g * 8;
      f32x4 a0, a1, c0, c1;
#pragma unroll
      for (int r = 0; r < 4; ++r) {
        a0[r] = q[bf][kb][r]; a1[r] = q[bf][kb][r + 4];
        c0[r] = p[bf][kb][r]; c1[r] = p[bf][kb][r + 4];
      }
      *(f32x4*)o = a0; *(f32x4*)(o + 4) = a1;
      *(f32x4*)(o + 128) = c0; *(f32x4*)(o + 132) = c1;
    }
}

extern "C" void kernel_launch(void* const* d_in, const int* in_sizes, int n_in,
                              void* d_out, int out_size, void* d_ws, size_t ws_size,
                              hipStream_t stream) {
  const float* x  = (const float*)d_in[0];
  const float* W1 = (const float*)d_in[1];
  const float* b1 = (const float*)d_in[2];
  const float* W2 = (const float*)d_in[3];
  // d_in[4] = b2: affects only V's value, not its gradient -> unused.
  float* out = (float*)d_out;
  unsigned short* w1t = (unsigned short*)d_ws;  // 128 KB bf16 W1^T

  hipLaunchKernelGGL(hn_prep, dim3(256), dim3(256), 0, stream, W1, w1t);
  hipLaunchKernelGGL(hn_main, dim3(256), dim3(512), 0, stream,
                     x, W1, b1, W2, w1t, out);
}

// Round 3
// 344.964 us; speedup vs baseline: 1.1688x; 1.1360x over previous
//
#include <hip/hip_runtime.h>
#include <hip/hip_bf16.h>

typedef float f32x4 __attribute__((ext_vector_type(4)));
typedef __bf16 bf16x8 __attribute__((ext_vector_type(8)));
typedef unsigned short u16x4 __attribute__((ext_vector_type(4)));

#if defined(__has_builtin)
#if __has_builtin(__builtin_amdgcn_exp2f)
#define EXP2F(x) __builtin_amdgcn_exp2f(x)
#else
#define EXP2F(x) exp2f(x)
#endif
#if __has_builtin(__builtin_amdgcn_rcpf)
#define RCPF(x) __builtin_amdgcn_rcpf(x)
#else
#define RCPF(x) (1.0f/(x))
#endif
#else
#define EXP2F(x) exp2f(x)
#define RCPF(x) (1.0f/(x))
#endif

#define MFMA16(a,b,c) __builtin_amdgcn_mfma_f32_16x16x32_bf16((a),(b),(c),0,0,0)

__device__ __forceinline__ unsigned short f2bf(float f) {
  return __builtin_bit_cast(unsigned short, (__bf16)f);
}

// Build permuted W1^T in d_ws: W1Tg[rho][iota], bf16.
//   rho: jb=rho>>5, jf=(rho>>4)&1, a=(rho>>2)&3, c=rho&3  -> j = jb*32 + a*8 + jf*4 + c   [pi]
//   iota: kb=io>>5,  u=(io>>3)&3,  v=io&7                 -> i = kb*32 + (v>>2)*16 + u*4 + (v&3)  [sigma]
__global__ __launch_bounds__(256) void hn_prep(const float* __restrict__ W1,
                                               unsigned short* __restrict__ W1T) {
  int t = blockIdx.x * 256 + threadIdx.x;  // t = rho*128 + iota
  int rho = t >> 7, io = t & 127;
  int j = (rho >> 5) * 32 + ((rho >> 2) & 3) * 8 + ((rho >> 4) & 1) * 4 + (rho & 3);
  int i = (io >> 5) * 32 + ((io & 7) >> 2) * 16 + ((io >> 3) & 3) * 4 + (io & 7 & 3);
  W1T[t] = f2bf(W1[i * 512 + j]);
}

// One block = 256 batch rows (8 waves x 32 rows). All 10 steps in-kernel.
// Zero cross-lane exchanges: pi/sigma permutations align C-layouts with frag layouts.
__global__ __launch_bounds__(512, 2) void hn_main(
    const float* __restrict__ x, const float* __restrict__ W1,
    const float* __restrict__ b1, const float* __restrict__ W2,
    const unsigned short* __restrict__ W1T, float* __restrict__ out) {
  __shared__ __align__(16) char w1l[131072];  // W1 bf16 [128 i][512 j] natural, ^((i&7)<<4)
  __shared__ __align__(16) float b1s[512];    // b1 * 2*log2(e)
  __shared__ __align__(16) float w2s[512];

  const int tid = threadIdx.x;
  const int lane = tid & 63;
  const int w = tid >> 6;
  const int m = lane & 15;
  const int g = lane >> 4;

  // ---- stage natural W1 -> LDS (bwd A-frags: j-contiguous 16B runs)
  for (int it = tid; it < 16384; it += 512) {
    int flat = it << 2;            // element index = i*512 + j
    int i = flat >> 9;
    f32x4 v = *(const f32x4*)(W1 + flat);
    u16x4 pk;
#pragma unroll
    for (int c = 0; c < 4; ++c) pk[c] = f2bf(v[c]);
    int ba = flat << 1;
    *(u16x4*)(w1l + (ba ^ ((i & 7) << 4))) = pk;
  }
  if (tid < 512) {
    b1s[tid] = b1[tid] * 2.8853900817779268f;
    w2s[tid] = W2[tid];
  }
  __syncthreads();

  const int b0 = blockIdx.x * 256 + w * 32;

  // q/p in sigma layout: q[bf][kb][r] = (row b0+16bf+m, i = 32kb + 16*(r>>2) + 4g + (r&3))
  float q[2][4][8], p[2][4][8];
#pragma unroll
  for (int bf = 0; bf < 2; ++bf)
#pragma unroll
    for (int kb = 0; kb < 4; ++kb) {
      const float* r0 = x + (long)(b0 + 16 * bf + m) * 256 + kb * 32 + g * 4;
#pragma unroll
      for (int h = 0; h < 2; ++h) {
        f32x4 qv = *(const f32x4*)(r0 + h * 16);
        f32x4 pv = *(const f32x4*)(r0 + h * 16 + 128);
#pragma unroll
        for (int rr = 0; rr < 4; ++rr) {
          q[bf][kb][4 * h + rr] = qv[rr];
          p[bf][kb][4 * h + rr] = pv[rr];
        }
      }
    }

  // lane-constant bases
  const char* aptr = (const char*)W1T + m * 256 + g * 16;  // fwd A: row rho=..+m, iota-chunk
  const int s45 = (m & 3) << 4, s6 = (m & 4) << 4;
  const int ybase = ((m * 1024 + g * 16) ^ s45);            // bwd A from LDS

#pragma unroll 1
  for (int step = 0; step < 10; ++step) {
    f32x4 gacc[2][8];  // C: col b = m+16bf, row i = 16nf + 4g + rr
#pragma unroll
    for (int bf = 0; bf < 2; ++bf)
#pragma unroll
      for (int nf = 0; nf < 8; ++nf) gacc[bf][nf] = f32x4{0.f, 0.f, 0.f, 0.f};

#pragma unroll 2
    for (int jblk = 0; jblk < 16; ++jblk) {
      // ---- forward: z tile. A = W1Tg rows (pi-ordered j), B = q (sigma order).
      f32x4 z[2][2];
      z[0][0] = f32x4{0.f,0.f,0.f,0.f}; z[0][1] = f32x4{0.f,0.f,0.f,0.f};
      z[1][0] = f32x4{0.f,0.f,0.f,0.f}; z[1][1] = f32x4{0.f,0.f,0.f,0.f};
#pragma unroll
      for (int kb = 0; kb < 4; ++kb) {
        bf16x8 qb0, qb1;
#pragma unroll
        for (int r = 0; r < 8; ++r) {
          qb0[r] = (__bf16)q[0][kb][r];
          qb1[r] = (__bf16)q[1][kb][r];
        }
#pragma unroll
        for (int jf = 0; jf < 2; ++jf) {
          bf16x8 a = *(const bf16x8*)(aptr + jblk * 8192 + jf * 4096 + kb * 64);
          z[jf][0] = MFMA16(a, qb0, z[jf][0]);
          z[jf][1] = MFMA16(a, qb1, z[jf][1]);
        }
      }
      // ---- activation: s = W2[j] * sech^2(z + b1[j]); z C-row (jf,rr) <-> j = 32jblk+8g+4jf+rr
      float s8[2][8];  // [bf][r]: r = 4*jf + rr  == bwd B-frag element order
#pragma unroll
      for (int jf = 0; jf < 2; ++jf) {
        f32x4 b1v = *(const f32x4*)(b1s + jblk * 32 + g * 8 + jf * 4);
        f32x4 w2v = *(const f32x4*)(w2s + jblk * 32 + g * 8 + jf * 4);
#pragma unroll
        for (int bf = 0; bf < 2; ++bf)
#pragma unroll
          for (int rr = 0; rr < 4; ++rr) {
            float zz = fmaf(z[jf][bf][rr], 2.8853900817779268f, b1v[rr]);
            float e = EXP2F(zz);                 // e^(2(z+b1))
            float u = RCPF(e + 1.f);
            float th = fmaf(-2.f, u, 1.f);       // tanh
            s8[bf][jf * 4 + rr] = fmaf(-th * th, w2v[rr], w2v[rr]);
          }
      }
      bf16x8 sB0, sB1;
#pragma unroll
      for (int r = 0; r < 8; ++r) {
        sB0[r] = (__bf16)s8[0][r];
        sB1[r] = (__bf16)s8[1][r];
      }
      // ---- backward: gacc += W1(A, natural from LDS) * s^T(B). k order = natural j.
      const int joff = (jblk * 64) ^ s6;
#pragma unroll
      for (int nf = 0; nf < 8; ++nf) {
        bf16x8 af = *(const bf16x8*)(w1l + ybase + nf * 16384 + joff);
        gacc[0][nf] = MFMA16(af, sB0, gacc[0][nf]);
        gacc[1][nf] = MFMA16(af, sB1, gacc[1][nf]);
      }
    }

    // q += dt * p_old  (gacc was computed from old q)
#pragma unroll
    for (int bf = 0; bf < 2; ++bf)
#pragma unroll
      for (int kb = 0; kb < 4; ++kb)
#pragma unroll
        for (int r = 0; r < 8; ++r)
          q[bf][kb][r] = fmaf(0.1f, p[bf][kb][r], q[bf][kb][r]);

    // p -= dt * g : gacc C-layout == p sigma-frag layout, pure f32, static indices
#pragma unroll
    for (int bf = 0; bf < 2; ++bf)
#pragma unroll
      for (int kb = 0; kb < 4; ++kb)
#pragma unroll
        for (int r = 0; r < 8; ++r)
          p[bf][kb][r] = fmaf(-0.1f, gacc[bf][2 * kb + (r >> 2)][r & 3], p[bf][kb][r]);

    __syncthreads();  // phase-lock waves (L1 locality on W1Tg slices)
  }

  // ---- store concat(q, p) with the same sigma addressing
#pragma unroll
  for (int bf = 0; bf < 2; ++bf)
#pragma unroll
    for (int kb = 0; kb < 4; ++kb) {
      float* o = out + (long)(b0 + 16 * bf + m) * 256 + kb * 32 + g * 4;
#pragma unroll
      for (int h = 0; h < 2; ++h) {
        f32x4 qv, pv;
#pragma unroll
        for (int rr = 0; rr < 4; ++rr) {
          qv[rr] = q[bf][kb][4 * h + rr];
          pv[rr] = p[bf][kb][4 * h + rr];
        }
        *(f32x4*)(o + h * 16) = qv;
        *(f32x4*)(o + h * 16 + 128) = pv;
      }
    }
}

extern "C" void kernel_launch(void* const* d_in, const int* in_sizes, int n_in,
                              void* d_out, int out_size, void* d_ws, size_t ws_size,
                              hipStream_t stream) {
  const float* x  = (const float*)d_in[0];
  const float* W1 = (const float*)d_in[1];
  const float* b1 = (const float*)d_in[2];
  const float* W2 = (const float*)d_in[3];
  // d_in[4] = b2: affects only V's value, not its gradient -> unused.
  float* out = (float*)d_out;
  unsigned short* w1t = (unsigned short*)d_ws;  // 128 KB bf16 permuted W1^T

  hipLaunchKernelGGL(hn_prep, dim3(256), dim3(256), 0, stream, W1, w1t);
  hipLaunchKernelGGL(hn_main, dim3(256), dim3(512), 0, stream,
                     x, W1, b1, W2, w1t, out);
}